// Round 18
// baseline (108.596 us; speedup 1.0000x reference)
//
#include <hip/hip_runtime.h>

#define NUM_CLASSES 80
constexpr int Bn = 8;
constexpr int Gn = 128;
constexpr int An = 131072;

constexpr int TB   = 256;   // 4 waves: 2 storer + 2 compute
constexpr int BBLK = 512;   // anchors per block (4 per compute thread)

// out layout: cls (B,A,80) | reg (B,A,4) | states (B,A)
constexpr size_t CLS_OFF = 0;
constexpr size_t REG_OFF = (size_t)Bn * An * NUM_CLASSES;
constexpr size_t ST_OFF  = REG_OFF + (size_t)Bn * An * 4;

__global__ __launch_bounds__(TB, 4) void targets_kernel(
    const float* __restrict__ ann,      // (B,G,5) x1,y1,x2,y2,label
    const float* __restrict__ anchors,  // (A,4)
    float* __restrict__ out)
{
#pragma clang fp contract(off)
    const int tid  = threadIdx.x;
    const int lane = tid & 63;
    const int wv   = tid >> 6;
    const int b    = blockIdx.y;
    const int base = blockIdx.x * BBLK;

    // wave-private staging for the two compute waves (no barrier needed:
    // single-wave ds_write -> ds_read ordering is via lgkmcnt, R4-validated)
    __shared__ float4 sbox[2][Gn];
    __shared__ float  sarea[2][Gn];
    __shared__ float  slabel[2][Gn];

    float4* cls_blk = reinterpret_cast<float4*>(
        out + CLS_OFF + ((size_t)b * An + base) * NUM_CLASSES);

    int a = 0;
    int mylab[4] = { -1, -1, -1, -1 };

    if (wv < 2) {
        // ---- STORER waves (tid 0..127): pure zero-store stream ----
        // 80 back-to-back dwordx4 stores each = 160 KB/block of cls zeros.
        // No LDS, no VALU chains, no dependencies: replicates the fill
        // kernel's instruction stream, paced only by store-queue drain.
        const float4 z = make_float4(0.f, 0.f, 0.f, 0.f);
        #pragma unroll 8
        for (int i = 0; i < 80; ++i)
            cls_blk[tid + i * 128] = z;
    } else {
        // ---- COMPUTE waves (tid 128..255): pure VALU/LDS main loop ----
        const int cw   = wv - 2;      // 0 or 1
        const int ctid = tid - 128;   // 0..127
        a = base + ctid * 4;

        // anchor loads first (in flight during staging)
        float4 av[4];
        #pragma unroll
        for (int j = 0; j < 4; ++j)
            av[j] = *reinterpret_cast<const float4*>(anchors + (size_t)(a + j) * 4);

        // wave-private staging of all 128 boxes
        #pragma unroll
        for (int i = lane; i < Gn; i += 64) {
            const float* p = ann + ((size_t)b * Gn + i) * 5;
            const float x1 = p[0], y1 = p[1], x2 = p[2], y2 = p[3];
            sbox[cw][i]   = make_float4(x1, y1, x2, y2);
            sarea[cw][i]  = (x2 - x1) * (y2 - y1);   // ref op order
            slabel[cw][i] = p[4];
        }

        float ax1[4], ay1[4], ax2[4], ay2[4];
        float wa[4], ha[4], area_a[4], interB[4], uniB[4];
        int besti[4];
        #pragma unroll
        for (int j = 0; j < 4; ++j) {
            ax1[j] = av[j].x; ay1[j] = av[j].y; ax2[j] = av[j].z; ay2[j] = av[j].w;
            wa[j] = ax2[j] - ax1[j];
            ha[j] = ay2[j] - ay1[j];
            area_a[j] = wa[j] * ha[j];      // ref op order
            interB[j] = -1.0f;              // sentinel: g=0 wins first compare
            uniB[j]   = 1.0f;
            besti[j]  = 0;
        }

        #pragma unroll 2
        for (int g = 0; g < Gn; ++g) {
            const float4 bv = sbox[cw][g];       // broadcast ds_read_b128
            const float area_b = sarea[cw][g];   // broadcast ds_read_b32
            #pragma unroll
            for (int j = 0; j < 4; ++j) {
                float iw = fminf(ax2[j], bv.z) - fmaxf(ax1[j], bv.x);
                iw = fmaxf(iw, 0.0f);
                float ih = fminf(ay2[j], bv.w) - fmaxf(ay1[j], bv.y);
                ih = fmaxf(ih, 0.0f);
                const float inter = iw * ih;
                const float uni = (area_a[j] + area_b) - inter;  // ref order, > 0
                // iou_g > iou_best <=> inter*uniB > interB*uni (both unions > 0)
                const bool upd = (inter * uniB[j]) > (interB[j] * uni);
                interB[j] = upd ? inter : interB[j];
                uniB[j]   = upd ? uni   : uniB[j];
                besti[j]  = upd ? g     : besti[j];
            }
        }

        // states: 4 adjacent anchors -> one float4 store
        float st[4];
        #pragma unroll
        for (int j = 0; j < 4; ++j) {
            const float best = interB[j] / fmaxf(uniB[j], 1e-8f);  // exact ref div
            st[j] = (best >= 0.5f) ? 1.0f : ((best < 0.4f) ? 0.0f : -1.0f);
        }
        *reinterpret_cast<float4*>(out + ST_OFF + (size_t)b * An + a) =
            make_float4(st[0], st[1], st[2], st[3]);

        #pragma unroll
        for (int j = 0; j < 4; ++j) {
            const float4 gt = sbox[cw][besti[j]];
            float4 rv;
            rv.x = ((gt.x - ax1[j]) / wa[j]) / 0.2f;
            rv.y = ((gt.y - ay1[j]) / ha[j]) / 0.2f;
            rv.z = ((gt.z - ax2[j]) / wa[j]) / 0.2f;
            rv.w = ((gt.w - ay2[j]) / ha[j]) / 0.2f;
            *reinterpret_cast<float4*>(out + REG_OFF + ((size_t)b * An + a + j) * 4) = rv;
            mylab[j] = (st[j] == 1.0f) ? (int)slabel[cw][besti[j]] : -1;
        }
    }

    // single barrier: storer waves arrive with vmcnt(0) (zeros complete);
    // compute waves arrive after the loop -> patches below are ordered.
    __syncthreads();

    if (wv >= 2) {
        // each compute thread patches its OWN 4 anchors' one-hot dwords
        #pragma unroll
        for (int j = 0; j < 4; ++j)
            if (mylab[j] >= 0)
                out[CLS_OFF + ((size_t)b * An + a + j) * NUM_CLASSES + mylab[j]] = 1.0f;
    }
}

extern "C" void kernel_launch(void* const* d_in, const int* in_sizes, int n_in,
                              void* d_out, int out_size, void* d_ws, size_t ws_size,
                              hipStream_t stream) {
    const float* ann     = (const float*)d_in[0];   // (8,128,5)
    const float* anchors = (const float*)d_in[1];   // (131072,4)
    float* out = (float*)d_out;

    dim3 grid(An / BBLK, Bn, 1);   // 256 x 8 = 2048 blocks (4 resident / CU)
    dim3 block(TB, 1, 1);
    targets_kernel<<<grid, block, 0, stream>>>(ann, anchors, out);
}

// Round 19
// 75.511 us; speedup vs baseline: 1.4381x; 1.4381x over previous
//
#include <hip/hip_runtime.h>

#define NUM_CLASSES 80
constexpr int Bn = 8;
constexpr int Gn = 128;
constexpr int An = 131072;

constexpr int TB   = 256;   // threads per block (4 waves)
constexpr int BBLK = 512;   // anchors per block (2 per thread)

constexpr int CH    = 8;                       // store-burst chunks
constexpr int ST_PC = (BBLK * 20) / TB / CH;   // 5 zero-stores per burst
constexpr int G_PC  = Gn / CH;                 // 16 g-iters per chunk period

// out layout: cls (B,A,80) | reg (B,A,4) | states (B,A)
constexpr size_t CLS_OFF = 0;
constexpr size_t REG_OFF = (size_t)Bn * An * NUM_CLASSES;
constexpr size_t ST_OFF  = REG_OFF + (size_t)Bn * An * 4;

__global__ __launch_bounds__(TB, 4) void targets_kernel(
    const float* __restrict__ ann,      // (B,G,5) x1,y1,x2,y2,label
    const float* __restrict__ anchors,  // (A,4)
    float* __restrict__ out)
{
#pragma clang fp contract(off)
    const int tid  = threadIdx.x;
    const int wv   = tid >> 6;          // wave id 0..3
    const int b    = blockIdx.y;
    const int base = blockIdx.x * BBLK;
    // PER-WAVE phase: 16 resident waves/CU occupy all 16 offsets of the
    // 16-iter burst period (gen1: y=0..3 -> 0..15; gen2: y=4..7 -> same).
    const int ph   = (b * 4 + wv) & 15;

    __shared__ float4 sbox[Gn];
    __shared__ float  sarea[Gn];
    __shared__ float  slabel[Gn];
    __shared__ int    slab[BBLK];

    if (tid < Gn) {
        const float* p = ann + ((size_t)b * Gn + tid) * 5;
        const float x1 = p[0], y1 = p[1], x2 = p[2], y2 = p[3];
        sbox[tid]   = make_float4(x1, y1, x2, y2);
        sarea[tid]  = (x2 - x1) * (y2 - y1);   // ref op order
        slabel[tid] = p[4];
    }

    // anchor loads issued before the barrier (in flight across it)
    const int a = base + tid * 2;
    const float4 av0 = *reinterpret_cast<const float4*>(anchors + (size_t)a * 4);
    const float4 av1 = *reinterpret_cast<const float4*>(anchors + (size_t)a * 4 + 4);

    __syncthreads();   // staging visible

    float4* cls_blk = reinterpret_cast<float4*>(
        out + CLS_OFF + ((size_t)b * An + base) * NUM_CLASSES);
    const float4 z = make_float4(0.f, 0.f, 0.f, 0.f);

    const float ax1[2] = { av0.x, av1.x };
    const float ay1[2] = { av0.y, av1.y };
    const float ax2[2] = { av0.z, av1.z };
    const float ay2[2] = { av0.w, av1.w };
    float wa[2], ha[2], area_a[2], interB[2], uniB[2];
    int besti[2];
    #pragma unroll
    for (int j = 0; j < 2; ++j) {
        wa[j] = ax2[j] - ax1[j];
        ha[j] = ay2[j] - ay1[j];
        area_a[j] = wa[j] * ha[j];      // ref op order
        interB[j] = -1.0f;              // sentinel: g=0 wins first compare
        uniB[j]   = 1.0f;
        besti[j]  = 0;
    }

    auto g_iter = [&](int g) {
        const float4 bv = sbox[g];        // broadcast ds_read_b128
        const float area_b = sarea[g];    // broadcast ds_read_b32
        #pragma unroll
        for (int j = 0; j < 2; ++j) {
            float iw = fminf(ax2[j], bv.z) - fmaxf(ax1[j], bv.x);
            iw = fmaxf(iw, 0.0f);
            float ih = fminf(ay2[j], bv.w) - fmaxf(ay1[j], bv.y);
            ih = fmaxf(ih, 0.0f);
            const float inter = iw * ih;
            const float uni = (area_a[j] + area_b) - inter;  // ref order, > 0
            // iou_g > iou_best <=> inter*uniB > interB*uni (both unions > 0)
            const bool upd = (inter * uniB[j]) > (interB[j] * uni);
            interB[j] = upd ? inter : interB[j];
            uniB[j]   = upd ? uni   : uniB[j];
            besti[j]  = upd ? g     : besti[j];
        }
    };

    // wave-phase-staggered interleave: prologue of ph (0..15) g-iters, then
    // 8 chunks of {5 zero-stores, 16 g-iters}; last chunk short by ph.
    // Burst positions: ph, ph+16, ..., ph+112 (all < 128). Total g = 128.
    int g = 0;
    for (; g < ph; ++g) g_iter(g);      // rolled, <=15 iters

    #pragma unroll
    for (int sc = 0; sc < CH; ++sc) {
        #pragma unroll
        for (int i = 0; i < ST_PC; ++i)
            cls_blk[tid + (sc * ST_PC + i) * TB] = z;   // data-independent

        if (sc < CH - 1) {
            #pragma unroll 4
            for (int k = 0; k < G_PC; ++k) g_iter(g + k);  // fixed-trip chunk
            g += G_PC;
        } else {
            for (; g < Gn; ++g) g_iter(g);                 // tail (16 - ph)
        }
    }

    // states (float2: this thread's 2 anchors are adjacent)
    float st[2];
    #pragma unroll
    for (int j = 0; j < 2; ++j) {
        const float best = interB[j] / fmaxf(uniB[j], 1e-8f);  // exact ref div
        st[j] = (best >= 0.5f) ? 1.0f : ((best < 0.4f) ? 0.0f : -1.0f);
    }
    *reinterpret_cast<float2*>(out + ST_OFF + (size_t)b * An + a) =
        make_float2(st[0], st[1]);

    #pragma unroll
    for (int j = 0; j < 2; ++j) {
        const float4 gt = sbox[besti[j]];
        float4 rv;
        rv.x = ((gt.x - ax1[j]) / wa[j]) / 0.2f;
        rv.y = ((gt.y - ay1[j]) / ha[j]) / 0.2f;
        rv.z = ((gt.z - ax2[j]) / wa[j]) / 0.2f;
        rv.w = ((gt.w - ay2[j]) / ha[j]) / 0.2f;
        *reinterpret_cast<float4*>(out + REG_OFF + ((size_t)b * An + a + j) * 4) = rv;
        slab[tid * 2 + j] = (st[j] == 1.0f) ? (int)slabel[besti[j]] : -1;
    }

    // barrier: slab visible; vmcnt(0) drain orders zero-stores before patches
    __syncthreads();

    // sparse patch: one dword per positive anchor (lines still L2-resident)
    #pragma unroll
    for (int k = tid; k < BBLK; k += TB) {
        const int lab = slab[k];
        if (lab >= 0)
            out[CLS_OFF + ((size_t)b * An + base + k) * NUM_CLASSES + lab] = 1.0f;
    }
}

extern "C" void kernel_launch(void* const* d_in, const int* in_sizes, int n_in,
                              void* d_out, int out_size, void* d_ws, size_t ws_size,
                              hipStream_t stream) {
    const float* ann     = (const float*)d_in[0];   // (8,128,5)
    const float* anchors = (const float*)d_in[1];   // (131072,4)
    float* out = (float*)d_out;

    dim3 grid(An / BBLK, Bn, 1);   // 256 x 8 = 2048 blocks (4 resident / CU)
    dim3 block(TB, 1, 1);
    targets_kernel<<<grid, block, 0, stream>>>(ann, anchors, out);
}